// Round 3
// baseline (432.853 us; speedup 1.0000x reference)
//
#include <hip/hip_runtime.h>
#include <hip/hip_bf16.h>

typedef __bf16 bf16_t;
typedef __bf16 bf16x8 __attribute__((ext_vector_type(8)));
typedef float  f32x4  __attribute__((ext_vector_type(4)));

#define DEV __device__ __forceinline__

static constexpr int QN    = 8192;
static constexpr int NW    = 5;
static constexpr int D     = 640;
static constexpr int INNER = 512;
static constexpr int MQ    = QN * NW;     // 40960 q rows

DEV float wredsum(float x) {
#pragma unroll
  for (int o = 32; o > 0; o >>= 1) x += __shfl_xor(x, o, 64);
  return x;
}

// async 16B-per-lane global->LDS copy; LDS dest = wave-uniform base + lane*16
DEV void gl_lds16(const bf16_t* g, bf16_t* l) {
  __builtin_amdgcn_global_load_lds(
      (const __attribute__((address_space(1))) unsigned int*)g,
      (__attribute__((address_space(3))) unsigned int*)l, 16, 0, 0);
}

// ---------------- LN + hi/lo bf16 split, one wave per row ----------------
__global__ __launch_bounds__(256) void ln_split_kernel(
    const float* __restrict__ q, const float* __restrict__ k,
    const float* __restrict__ v, const float* __restrict__ g,
    const float* __restrict__ b, bf16_t* __restrict__ Ah,
    bf16_t* __restrict__ Al, int row0) {
  int lr   = blockIdx.x * 4 + (threadIdx.x >> 6);
  int lane = threadIdx.x & 63;
  int rg   = row0 + lr;
  const float* src = (rg < MQ) ? q + (size_t)rg * D
                   : (rg < MQ + QN) ? k + (size_t)(rg - MQ) * D
                   : v + (size_t)(rg - MQ - QN) * D;
  float2 x[5];
  float s = 0.f, ss = 0.f;
#pragma unroll
  for (int j = 0; j < 5; ++j) {
    x[j] = ((const float2*)src)[lane + 64 * j];
    s  += x[j].x + x[j].y;
    ss += x[j].x * x[j].x + x[j].y * x[j].y;
  }
  s = wredsum(s); ss = wredsum(ss);
  float m  = s * (1.f / D);
  float rs = rsqrtf(ss * (1.f / D) - m * m + 1e-5f);
#pragma unroll
  for (int j = 0; j < 5; ++j) {
    float2 gg = ((const float2*)g)[lane + 64 * j];
    float2 bb = ((const float2*)b)[lane + 64 * j];
    float xn0 = (x[j].x - m) * rs * gg.x + bb.x;
    float xn1 = (x[j].y - m) * rs * gg.y + bb.y;
    bf16_t h0 = (bf16_t)xn0, h1 = (bf16_t)xn1;
    union { bf16_t bb2[2]; unsigned u; } ph, pl;
    ph.bb2[0] = h0; ph.bb2[1] = h1;
    pl.bb2[0] = (bf16_t)(xn0 - (float)h0);
    pl.bb2[1] = (bf16_t)(xn1 - (float)h1);
    ((unsigned*)(Ah + (size_t)lr * D))[lane + 64 * j] = ph.u;
    ((unsigned*)(Al + (size_t)lr * D))[lane + 64 * j] = pl.u;
  }
}

// ------- transpose + hi/lo split, LDS-tiled 64x64 for coalesced writes -------
// src is R x C f32; dst{H,L} are C x R bf16. grid = (R/64)*(C/64), 256 thr.
__global__ __launch_bounds__(256) void transpose_split_kernel(
    const float* __restrict__ src, bf16_t* __restrict__ dstH,
    bf16_t* __restrict__ dstL, int R, int C) {
  __shared__ unsigned T[64][65];
  int tiles_c = C >> 6;
  int tr = blockIdx.x / tiles_c, tc = blockIdx.x - tr * tiles_c;
  int r0 = tr << 6, c0 = tc << 6;
  int lane = threadIdx.x & 63, wid = threadIdx.x >> 6;
#pragma unroll
  for (int i = 0; i < 16; ++i) {
    int r = wid * 16 + i;
    float x = src[(size_t)(r0 + r) * C + c0 + lane];
    bf16_t h = (bf16_t)x;
    union { bf16_t b2[2]; unsigned u; } p;
    p.b2[0] = h; p.b2[1] = (bf16_t)(x - (float)h);
    T[r][lane] = p.u;
  }
  __syncthreads();
#pragma unroll
  for (int i = 0; i < 16; ++i) {
    int c = wid * 16 + i;
    union { bf16_t b2[2]; unsigned u; } p;
    p.u = T[lane][c];
    dstH[(size_t)(c0 + c) * R + r0 + lane] = p.b2[0];
    dstL[(size_t)(c0 + c) * R + r0 + lane] = p.b2[1];
  }
}

// ---------------- GEMM1: 128x128 tile, BK=32, double-buffered LDS ----------------
// min-2-phase schedule (one barrier per K-step): STAGE(next,buf^1) -> ds_read(cur)
// -> MFMA -> __syncthreads (drains vmcnt(0), protects buffer overwrite).
// LDS 16B-granule XOR swizzle: staged via pre-swizzled GLOBAL source column,
// read with (quad ^ sx).  MODE0 bm is k/v-interleave permuted for XCD balance.
template <int MODE>
__global__ __launch_bounds__(256) void gemm1_kernel(
    const bf16_t* __restrict__ Ah, const bf16_t* __restrict__ Al,
    const bf16_t* __restrict__ Bh, const bf16_t* __restrict__ Bl,
    float* __restrict__ Fkv, const float* __restrict__ Fk,
    float* __restrict__ Sq, float* __restrict__ Sqq,
    float* __restrict__ Sqk, int qrow0) {
  __shared__ __align__(16) bf16_t AhS[2][128 * 32];
  __shared__ __align__(16) bf16_t AlS[2][128 * 32];
  __shared__ __align__(16) bf16_t BhS[2][128 * 32];
  __shared__ __align__(16) bf16_t BlS[2][128 * 32];
  const unsigned wg = (blockIdx.x & 7) * (gridDim.x >> 3) + (blockIdx.x >> 3);
  const int bn = wg & 3;
  const int bm0 = wg >> 2;
  // MODE0: interleave 3-term (k, bm<64) and 1-term (v) blocks across XCD chunks
  const int bm = (MODE == 0) ? ((bm0 & 1) ? 64 + (bm0 >> 1) : (bm0 >> 1)) : bm0;
  const int t = threadIdx.x, lane = t & 63, wid = t >> 6;
  const int wr = wid >> 1, wc = wid & 1;
  const int lm = lane & 15, quad = lane >> 4;
  const bool T3 = (MODE == 1) || (bm < 64);
  const size_t arow0 = (size_t)bm * 128;
  const size_t brow0 = (size_t)bn * 128;
  const int cb = wid * 2;
  const int sx = (lm >> 1) & 3;  // == (row>>1)&3 for rows wr*64+i*16+lm

  auto STAGE = [&](int k0, int buf) {
#pragma unroll
    for (int tt = 0; tt < 2; ++tt) {
      int chunk = (cb + tt) * 64 + lane;
      int r = chunk >> 2;
      int c8 = (((chunk & 3) ^ ((r >> 1) & 3)) * 8);  // inverse-swizzled source
      gl_lds16(Ah + (arow0 + r) * 640 + k0 + c8, &AhS[buf][(cb + tt) * 512]);
      gl_lds16(Bh + (brow0 + r) * 640 + k0 + c8, &BhS[buf][(cb + tt) * 512]);
      if (T3) {
        gl_lds16(Al + (arow0 + r) * 640 + k0 + c8, &AlS[buf][(cb + tt) * 512]);
        gl_lds16(Bl + (brow0 + r) * 640 + k0 + c8, &BlS[buf][(cb + tt) * 512]);
      }
    }
  };

  f32x4 acc[4][4] = {};
  STAGE(0, 0);
  __syncthreads();  // stage(0) landed (vmcnt(0) implied)

  for (int k0 = 0; k0 < 640; k0 += 32) {
    const int cur = (k0 >> 5) & 1;
    if (k0 + 32 < 640) STAGE(k0 + 32, cur ^ 1);  // overlaps reads+MFMA below
    bf16x8 ah[4], bh[4], al[4], bl[4];
#pragma unroll
    for (int i = 0; i < 4; ++i) {
      ah[i] = *(const bf16x8*)&AhS[cur][(wr * 64 + i * 16 + lm) * 32 + (quad ^ sx) * 8];
      bh[i] = *(const bf16x8*)&BhS[cur][(wc * 64 + i * 16 + lm) * 32 + (quad ^ sx) * 8];
    }
    if (T3) {
#pragma unroll
      for (int i = 0; i < 4; ++i) {
        al[i] = *(const bf16x8*)&AlS[cur][(wr * 64 + i * 16 + lm) * 32 + (quad ^ sx) * 8];
        bl[i] = *(const bf16x8*)&BlS[cur][(wc * 64 + i * 16 + lm) * 32 + (quad ^ sx) * 8];
      }
    }
    __builtin_amdgcn_s_setprio(1);
#pragma unroll
    for (int mi = 0; mi < 4; ++mi)
#pragma unroll
      for (int nj = 0; nj < 4; ++nj) {
        acc[mi][nj] =
            __builtin_amdgcn_mfma_f32_16x16x32_bf16(ah[mi], bh[nj], acc[mi][nj], 0, 0, 0);
        if (T3) {
          acc[mi][nj] =
              __builtin_amdgcn_mfma_f32_16x16x32_bf16(al[mi], bh[nj], acc[mi][nj], 0, 0, 0);
          acc[mi][nj] =
              __builtin_amdgcn_mfma_f32_16x16x32_bf16(ah[mi], bl[nj], acc[mi][nj], 0, 0, 0);
        }
      }
    __builtin_amdgcn_s_setprio(0);
    __syncthreads();  // all reads of cur done + stage(next) drained
  }

  if (MODE == 0) {
#pragma unroll
    for (int mi = 0; mi < 4; ++mi)
#pragma unroll
      for (int nj = 0; nj < 4; ++nj)
#pragma unroll
        for (int r = 0; r < 4; ++r) {
          int row = bm * 128 + wr * 64 + mi * 16 + quad * 4 + r;
          int col = bn * 128 + wc * 64 + nj * 16 + lm;
          Fkv[(size_t)row * INNER + col] = acc[mi][nj][r];
        }
  } else {
    const int head = bn * 2 + wc;
#pragma unroll
    for (int mi = 0; mi < 4; ++mi)
#pragma unroll
      for (int r = 0; r < 4; ++r) {
        int rowA = qrow0 + bm * 128 + wr * 64 + mi * 16 + quad * 4 + r;
        int qi   = (unsigned)rowA / NW;
        float s1 = 0.f, s2 = 0.f, s3 = 0.f;
#pragma unroll
        for (int nj = 0; nj < 4; ++nj) {
          float fq = acc[mi][nj][r];
          float fk = Fk[(size_t)qi * INNER + head * 64 + nj * 16 + lm];
          s1 += fq; s2 += fq * fq; s3 += fq * fk;
        }
#pragma unroll
        for (int o = 1; o < 16; o <<= 1) {
          s1 += __shfl_xor(s1, o, 64);
          s2 += __shfl_xor(s2, o, 64);
          s3 += __shfl_xor(s3, o, 64);
        }
        if (lm == 0) {
          size_t o = (size_t)rowA * 8 + head;
          Sq[o] = s1; Sqq[o] = s2; Sqk[o] = s3;
        }
      }
  }
}

// ---------------- dots + Y = dots .* f_v (bf16), fused ----------------
__global__ __launch_bounds__(256) void dots_y_kernel(
    const float* __restrict__ Fkv, const float* __restrict__ Sq,
    const float* __restrict__ Sqq, const float* __restrict__ Sqk,
    const float* __restrict__ vsp, const float* __restrict__ csp,
    bf16_t* __restrict__ Yh) {
  int wv   = blockIdx.x * 4 + (threadIdx.x >> 6);
  int lane = threadIdx.x & 63;
  int qi = wv >> 3, h = wv & 7;
  float fk = Fkv[(size_t)qi * INNER + h * 64 + lane];
  float fv = Fkv[(size_t)(QN + qi) * INNER + h * 64 + lane];
  float sk  = wredsum(fk);
  float skk = wredsum(fk * fk);
  float mk   = sk * (1.f / 64.f);
  float vark = skk * (1.f / 64.f) - mk * mk + 1e-6f;
  float nk   = sqrtf(skk);

  int n = (lane < NW) ? lane : 0;
  size_t si = (size_t)(qi * NW + n) * 8 + h;
  float s1 = Sq[si], s2 = Sqq[si], s3 = Sqk[si];
  float mq   = s1 * (1.f / 64.f);
  float varq = s2 * (1.f / 64.f) - mq * mq + 1e-6f;
  float nq   = sqrtf(s2);
  float cosv = s3 / (nq * nk);
  float vw   = 1.f / (fabsf(vark - varq) + 1e-6f);
  float cov  = (s3 - 64.f * mk * mq) / (64.f + 1e-6f);
  float sg   = 1.f / (1.f + expf(-cov));
  float vwsum = 0.f;
#pragma unroll
  for (int j = 0; j < NW; ++j) vwsum += __shfl(vw, j, 64);
  float dv = cosv + vsp[0] * vw / (vwsum + 1e-6f) + csp[0] * sg;
#pragma unroll
  for (int j = 0; j < NW; ++j) {
    float dvj = __shfl(dv, j, 64);
    Yh[(size_t)(qi * NW + j) * INNER + h * 64 + lane] = (bf16_t)(dvj * fv);
  }
}

// ---------------- GEMM2: out = Y @ W_out + b_out (1-term bf16) ----------------
__global__ __launch_bounds__(256) void gemm2_kernel(
    const bf16_t* __restrict__ Yh, const bf16_t* __restrict__ Bh,
    const float* __restrict__ bias, float* __restrict__ out) {
  __shared__ __align__(16) bf16_t AS[2][128 * 32];
  __shared__ __align__(16) bf16_t BS[2][128 * 32];
  const unsigned wg = (blockIdx.x & 7) * (gridDim.x >> 3) + (blockIdx.x >> 3);
  const int bn = wg % 5, bm = wg / 5;
  const int t = threadIdx.x, lane = t & 63, wid = t >> 6;
  const int wr = wid >> 1, wc = wid & 1;
  const int lm = lane & 15, quad = lane >> 4;
  const size_t arow0 = (size_t)bm * 128;
  const size_t brow0 = (size_t)bn * 128;
  const int cb = wid * 2;
  const int sx = (lm >> 1) & 3;

  auto STAGE = [&](int k0, int buf) {
#pragma unroll
    for (int tt = 0; tt < 2; ++tt) {
      int chunk = (cb + tt) * 64 + lane;
      int r = chunk >> 2;
      int c8 = (((chunk & 3) ^ ((r >> 1) & 3)) * 8);
      gl_lds16(Yh + (arow0 + r) * INNER + k0 + c8, &AS[buf][(cb + tt) * 512]);
      gl_lds16(Bh + (brow0 + r) * INNER + k0 + c8, &BS[buf][(cb + tt) * 512]);
    }
  };

  f32x4 acc[4][4] = {};
  STAGE(0, 0);
  __syncthreads();

  for (int k0 = 0; k0 < INNER; k0 += 32) {
    const int cur = (k0 >> 5) & 1;
    if (k0 + 32 < INNER) STAGE(k0 + 32, cur ^ 1);
    bf16x8 a[4], b[4];
#pragma unroll
    for (int i = 0; i < 4; ++i) {
      a[i] = *(const bf16x8*)&AS[cur][(wr * 64 + i * 16 + lm) * 32 + (quad ^ sx) * 8];
      b[i] = *(const bf16x8*)&BS[cur][(wc * 64 + i * 16 + lm) * 32 + (quad ^ sx) * 8];
    }
    __builtin_amdgcn_s_setprio(1);
#pragma unroll
    for (int mi = 0; mi < 4; ++mi)
#pragma unroll
      for (int nj = 0; nj < 4; ++nj)
        acc[mi][nj] =
            __builtin_amdgcn_mfma_f32_16x16x32_bf16(a[mi], b[nj], acc[mi][nj], 0, 0, 0);
    __builtin_amdgcn_s_setprio(0);
    __syncthreads();
  }
#pragma unroll
  for (int mi = 0; mi < 4; ++mi)
#pragma unroll
    for (int nj = 0; nj < 4; ++nj) {
      float bia = bias[bn * 128 + wc * 64 + nj * 16 + lm];
#pragma unroll
      for (int r = 0; r < 4; ++r) {
        int row = bm * 128 + wr * 64 + mi * 16 + quad * 4 + r;
        int col = bn * 128 + wc * 64 + nj * 16 + lm;
        out[(size_t)row * D + col] = acc[mi][nj][r] + bia;
      }
    }
}

extern "C" void kernel_launch(void* const* d_in, const int* in_sizes, int n_in,
                              void* d_out, int out_size, void* d_ws,
                              size_t ws_size, hipStream_t stream) {
  const float* q    = (const float*)d_in[0];
  const float* k    = (const float*)d_in[1];
  const float* v    = (const float*)d_in[2];
  const float* g    = (const float*)d_in[3];
  const float* b    = (const float*)d_in[4];
  const float* Win  = (const float*)d_in[5];
  const float* Wout = (const float*)d_in[6];
  const float* bout = (const float*)d_in[7];
  const float* vsp  = (const float*)d_in[8];
  const float* csp  = (const float*)d_in[9];
  float* out = (float*)d_out;

  char* w = (char*)d_ws;
  float* Fkv     = (float*)w;  w += (size_t)(2 * QN) * INNER * 4;   // 33.55 MB
  float* Sq      = (float*)w;  w += (size_t)MQ * 8 * 4;             // 1.31 MB
  float* Sqq     = (float*)w;  w += (size_t)MQ * 8 * 4;
  float* Sqk     = (float*)w;  w += (size_t)MQ * 8 * 4;
  bf16_t* Ah     = (bf16_t*)w; w += (size_t)MQ * D * 2;             // 52.4 MB
  bf16_t* Al     = (bf16_t*)w; w += (size_t)MQ * D * 2;             // 52.4 MB
  bf16_t* WinTh  = (bf16_t*)w; w += (size_t)INNER * D * 2;
  bf16_t* WinTl  = (bf16_t*)w; w += (size_t)INNER * D * 2;
  bf16_t* WoutTh = (bf16_t*)w; w += (size_t)D * INNER * 2;
  bf16_t* WoutTl = (bf16_t*)w; w += (size_t)D * INNER * 2;
  bf16_t* Yh = Ah;  // Ah dead after last gemm1; Yh (41.9 MB) fits in Ah (52.4 MB)

  transpose_split_kernel<<<dim3((D / 64) * (INNER / 64)), dim3(256), 0, stream>>>(
      Win, WinTh, WinTl, D, INNER);
  transpose_split_kernel<<<dim3((INNER / 64) * (D / 64)), dim3(256), 0, stream>>>(
      Wout, WoutTh, WoutTl, INNER, D);

  // --- k/v rows: LN-split then project -> Fkv (k 3-term, v 1-term) ---
  ln_split_kernel<<<dim3(2 * QN / 4), dim3(256), 0, stream>>>(
      q, k, v, g, b, Ah, Al, MQ);
  gemm1_kernel<0><<<dim3((2 * QN / 128) * 4), dim3(256), 0, stream>>>(
      Ah, Al, WinTh, WinTl, Fkv, nullptr, nullptr, nullptr, nullptr, 0);

  // --- all q rows in ONE launch (1280 blocks): fused stats ---
  ln_split_kernel<<<dim3(MQ / 4), dim3(256), 0, stream>>>(
      q, k, v, g, b, Ah, Al, 0);
  gemm1_kernel<1><<<dim3((MQ / 128) * 4), dim3(256), 0, stream>>>(
      Ah, Al, WinTh, WinTl, nullptr, Fkv, Sq, Sqq, Sqk, 0);

  // --- dots + Y, then output GEMM ---
  dots_y_kernel<<<dim3(QN * 8 / 4), dim3(256), 0, stream>>>(
      Fkv, Sq, Sqq, Sqk, vsp, csp, Yh);
  gemm2_kernel<<<dim3((MQ / 128) * 5), dim3(256), 0, stream>>>(
      Yh, WoutTh, bout, out);
}

// Round 4
// 427.925 us; speedup vs baseline: 1.0115x; 1.0115x over previous
//
#include <hip/hip_runtime.h>
#include <hip/hip_bf16.h>

typedef __bf16 bf16_t;
typedef __bf16 bf16x8 __attribute__((ext_vector_type(8)));
typedef float  f32x4  __attribute__((ext_vector_type(4)));

#define DEV __device__ __forceinline__

static constexpr int QN    = 8192;
static constexpr int NW    = 5;
static constexpr int D     = 640;
static constexpr int INNER = 512;
static constexpr int MQ    = QN * NW;     // 40960 q rows

DEV float wredsum(float x) {
#pragma unroll
  for (int o = 32; o > 0; o >>= 1) x += __shfl_xor(x, o, 64);
  return x;
}

// async 16B-per-lane global->LDS copy; LDS dest = wave-uniform base + lane*16
DEV void gl_lds16(const bf16_t* g, bf16_t* l) {
  __builtin_amdgcn_global_load_lds(
      (const __attribute__((address_space(1))) unsigned int*)g,
      (__attribute__((address_space(3))) unsigned int*)l, 16, 0, 0);
}

// ---------------- LN + hi/lo bf16 split, one wave per row ----------------
__global__ __launch_bounds__(256) void ln_split_kernel(
    const float* __restrict__ q, const float* __restrict__ k,
    const float* __restrict__ v, const float* __restrict__ g,
    const float* __restrict__ b, bf16_t* __restrict__ Ah,
    bf16_t* __restrict__ Al, int row0) {
  int lr   = blockIdx.x * 4 + (threadIdx.x >> 6);
  int lane = threadIdx.x & 63;
  int rg   = row0 + lr;
  const float* src = (rg < MQ) ? q + (size_t)rg * D
                   : (rg < MQ + QN) ? k + (size_t)(rg - MQ) * D
                   : v + (size_t)(rg - MQ - QN) * D;
  float2 x[5];
  float s = 0.f, ss = 0.f;
#pragma unroll
  for (int j = 0; j < 5; ++j) {
    x[j] = ((const float2*)src)[lane + 64 * j];
    s  += x[j].x + x[j].y;
    ss += x[j].x * x[j].x + x[j].y * x[j].y;
  }
  s = wredsum(s); ss = wredsum(ss);
  float m  = s * (1.f / D);
  float rs = rsqrtf(ss * (1.f / D) - m * m + 1e-5f);
#pragma unroll
  for (int j = 0; j < 5; ++j) {
    float2 gg = ((const float2*)g)[lane + 64 * j];
    float2 bb = ((const float2*)b)[lane + 64 * j];
    float xn0 = (x[j].x - m) * rs * gg.x + bb.x;
    float xn1 = (x[j].y - m) * rs * gg.y + bb.y;
    bf16_t h0 = (bf16_t)xn0, h1 = (bf16_t)xn1;
    union { bf16_t bb2[2]; unsigned u; } ph, pl;
    ph.bb2[0] = h0; ph.bb2[1] = h1;
    pl.bb2[0] = (bf16_t)(xn0 - (float)h0);
    pl.bb2[1] = (bf16_t)(xn1 - (float)h1);
    ((unsigned*)(Ah + (size_t)lr * D))[lane + 64 * j] = ph.u;
    ((unsigned*)(Al + (size_t)lr * D))[lane + 64 * j] = pl.u;
  }
}

// ------- transpose + hi/lo split, LDS-tiled 64x64 for coalesced writes -------
__global__ __launch_bounds__(256) void transpose_split_kernel(
    const float* __restrict__ src, bf16_t* __restrict__ dstH,
    bf16_t* __restrict__ dstL, int R, int C) {
  __shared__ unsigned T[64][65];
  int tiles_c = C >> 6;
  int tr = blockIdx.x / tiles_c, tc = blockIdx.x - tr * tiles_c;
  int r0 = tr << 6, c0 = tc << 6;
  int lane = threadIdx.x & 63, wid = threadIdx.x >> 6;
#pragma unroll
  for (int i = 0; i < 16; ++i) {
    int r = wid * 16 + i;
    float x = src[(size_t)(r0 + r) * C + c0 + lane];
    bf16_t h = (bf16_t)x;
    union { bf16_t b2[2]; unsigned u; } p;
    p.b2[0] = h; p.b2[1] = (bf16_t)(x - (float)h);
    T[r][lane] = p.u;
  }
  __syncthreads();
#pragma unroll
  for (int i = 0; i < 16; ++i) {
    int c = wid * 16 + i;
    union { bf16_t b2[2]; unsigned u; } p;
    p.u = T[lane][c];
    dstH[(size_t)(c0 + c) * R + r0 + lane] = p.b2[0];
    dstL[(size_t)(c0 + c) * R + r0 + lane] = p.b2[1];
  }
}

// ---------------- GEMM1: 128x128 tile, BK=32, single-buffer LDS ----------------
// R2-proven schedule: sync(stage ready) -> ds_read frags -> sync(reads done) ->
// issue next STAGE (async, hides under MFMA) -> MFMA.
// LDS 16B-granule XOR swizzle via pre-swizzled GLOBAL source column.
// MODE0 bm is k/v-interleave permuted for XCD load balance.
template <int MODE>
__global__ __launch_bounds__(256) void gemm1_kernel(
    const bf16_t* __restrict__ Ah, const bf16_t* __restrict__ Al,
    const bf16_t* __restrict__ Bh, const bf16_t* __restrict__ Bl,
    float* __restrict__ Fkv, const float* __restrict__ Fk,
    float* __restrict__ Sq, float* __restrict__ Sqq,
    float* __restrict__ Sqk, int qrow0) {
  __shared__ __align__(16) bf16_t AhS[128 * 32];
  __shared__ __align__(16) bf16_t AlS[128 * 32];
  __shared__ __align__(16) bf16_t BhS[128 * 32];
  __shared__ __align__(16) bf16_t BlS[128 * 32];
  const unsigned wg = (blockIdx.x & 7) * (gridDim.x >> 3) + (blockIdx.x >> 3);
  const int bn = wg & 3;
  const int bm0 = wg >> 2;
  // MODE0: interleave 3-term (k, bm<64) and 1-term (v) blocks across XCD chunks
  const int bm = (MODE == 0) ? ((bm0 & 1) ? 64 + (bm0 >> 1) : (bm0 >> 1)) : bm0;
  const int t = threadIdx.x, lane = t & 63, wid = t >> 6;
  const int wr = wid >> 1, wc = wid & 1;
  const int lm = lane & 15, quad = lane >> 4;
  const bool T3 = (MODE == 1) || (bm < 64);
  const size_t arow0 = (size_t)bm * 128;
  const size_t brow0 = (size_t)bn * 128;
  const int cb = wid * 2;
  const int sx = (lm >> 1) & 3;  // == (row>>1)&3 for rows wr*64+i*16+lm

  auto STAGE = [&](int k0) {
#pragma unroll
    for (int tt = 0; tt < 2; ++tt) {
      int chunk = (cb + tt) * 64 + lane;
      int r = chunk >> 2;
      int c8 = (((chunk & 3) ^ ((r >> 1) & 3)) * 8);  // inverse-swizzled source
      gl_lds16(Ah + (arow0 + r) * 640 + k0 + c8, &AhS[(cb + tt) * 512]);
      gl_lds16(Bh + (brow0 + r) * 640 + k0 + c8, &BhS[(cb + tt) * 512]);
      if (T3) {
        gl_lds16(Al + (arow0 + r) * 640 + k0 + c8, &AlS[(cb + tt) * 512]);
        gl_lds16(Bl + (brow0 + r) * 640 + k0 + c8, &BlS[(cb + tt) * 512]);
      }
    }
  };

  f32x4 acc[4][4] = {};
  STAGE(0);

  for (int k0 = 0; k0 < 640; k0 += 32) {
    __syncthreads();  // stage(k0) arrived (implicit vmcnt(0))
    bf16x8 ah[4], bh[4], al[4], bl[4];
#pragma unroll
    for (int i = 0; i < 4; ++i) {
      ah[i] = *(const bf16x8*)&AhS[(wr * 64 + i * 16 + lm) * 32 + (quad ^ sx) * 8];
      bh[i] = *(const bf16x8*)&BhS[(wc * 64 + i * 16 + lm) * 32 + (quad ^ sx) * 8];
    }
    if (T3) {
#pragma unroll
      for (int i = 0; i < 4; ++i) {
        al[i] = *(const bf16x8*)&AlS[(wr * 64 + i * 16 + lm) * 32 + (quad ^ sx) * 8];
        bl[i] = *(const bf16x8*)&BlS[(wc * 64 + i * 16 + lm) * 32 + (quad ^ sx) * 8];
      }
    }
    __syncthreads();  // all waves done reading -> safe to overwrite
    if (k0 + 32 < 640) STAGE(k0 + 32);  // async, hides under MFMA below
#pragma unroll
    for (int mi = 0; mi < 4; ++mi)
#pragma unroll
      for (int nj = 0; nj < 4; ++nj) {
        acc[mi][nj] =
            __builtin_amdgcn_mfma_f32_16x16x32_bf16(ah[mi], bh[nj], acc[mi][nj], 0, 0, 0);
        if (T3) {
          acc[mi][nj] =
              __builtin_amdgcn_mfma_f32_16x16x32_bf16(al[mi], bh[nj], acc[mi][nj], 0, 0, 0);
          acc[mi][nj] =
              __builtin_amdgcn_mfma_f32_16x16x32_bf16(ah[mi], bl[nj], acc[mi][nj], 0, 0, 0);
        }
      }
  }

  if (MODE == 0) {
#pragma unroll
    for (int mi = 0; mi < 4; ++mi)
#pragma unroll
      for (int nj = 0; nj < 4; ++nj)
#pragma unroll
        for (int r = 0; r < 4; ++r) {
          int row = bm * 128 + wr * 64 + mi * 16 + quad * 4 + r;
          int col = bn * 128 + wc * 64 + nj * 16 + lm;
          Fkv[(size_t)row * INNER + col] = acc[mi][nj][r];
        }
  } else {
    const int head = bn * 2 + wc;
#pragma unroll
    for (int mi = 0; mi < 4; ++mi)
#pragma unroll
      for (int r = 0; r < 4; ++r) {
        int rowA = qrow0 + bm * 128 + wr * 64 + mi * 16 + quad * 4 + r;
        int qi   = (unsigned)rowA / NW;
        float s1 = 0.f, s2 = 0.f, s3 = 0.f;
#pragma unroll
        for (int nj = 0; nj < 4; ++nj) {
          float fq = acc[mi][nj][r];
          float fk = Fk[(size_t)qi * INNER + head * 64 + nj * 16 + lm];
          s1 += fq; s2 += fq * fq; s3 += fq * fk;
        }
#pragma unroll
        for (int o = 1; o < 16; o <<= 1) {
          s1 += __shfl_xor(s1, o, 64);
          s2 += __shfl_xor(s2, o, 64);
          s3 += __shfl_xor(s3, o, 64);
        }
        if (lm == 0) {
          size_t o = (size_t)rowA * 8 + head;
          Sq[o] = s1; Sqq[o] = s2; Sqk[o] = s3;
        }
      }
  }
}

// ---------------- dots: writes Dv [MQ][8] f32 only (no Y expansion) ----------------
__global__ __launch_bounds__(256) void dots_kernel(
    const float* __restrict__ Fkv, const float* __restrict__ Sq,
    const float* __restrict__ Sqq, const float* __restrict__ Sqk,
    const float* __restrict__ vsp, const float* __restrict__ csp,
    float* __restrict__ Dv) {
  int wv   = blockIdx.x * 4 + (threadIdx.x >> 6);
  int lane = threadIdx.x & 63;
  int qi = wv >> 3, h = wv & 7;
  float fk = Fkv[(size_t)qi * INNER + h * 64 + lane];
  float sk  = wredsum(fk);
  float skk = wredsum(fk * fk);
  float mk   = sk * (1.f / 64.f);
  float vark = skk * (1.f / 64.f) - mk * mk + 1e-6f;
  float nk   = sqrtf(skk);

  int n = (lane < NW) ? lane : 0;
  size_t si = (size_t)(qi * NW + n) * 8 + h;
  float s1 = Sq[si], s2 = Sqq[si], s3 = Sqk[si];
  float mq   = s1 * (1.f / 64.f);
  float varq = s2 * (1.f / 64.f) - mq * mq + 1e-6f;
  float nq   = sqrtf(s2);
  float cosv = s3 / (nq * nk);
  float vw   = 1.f / (fabsf(vark - varq) + 1e-6f);
  float cov  = (s3 - 64.f * mk * mq) / (64.f + 1e-6f);
  float sg   = 1.f / (1.f + expf(-cov));
  float vwsum = 0.f;
#pragma unroll
  for (int j = 0; j < NW; ++j) vwsum += __shfl(vw, j, 64);
  float dv = cosv + vsp[0] * vw / (vwsum + 1e-6f) + csp[0] * sg;
  if (lane < NW) Dv[(size_t)(qi * NW + lane) * 8 + h] = dv;
}

// ---------------- GEMM2: out = (Dv .* Fv) @ W_out + b_out ----------------
// A-tile built on the fly: a[row][col] = (bf16)(Dv[row][col>>6] * Fkv_v[row/5][col]),
// reg-staged and ds_written into XOR-swizzled LDS (write-side swizzle).
// B staged via gl_lds16 with pre-swizzled source. R2-style 2-barrier schedule:
// reads -> sync -> issue B-stage + A-loads -> MFMA (hides latency) -> pack+ds_write -> sync.
__global__ __launch_bounds__(256) void gemm2_kernel(
    const float* __restrict__ Fkv, const float* __restrict__ Dv,
    const bf16_t* __restrict__ Bh, const float* __restrict__ bias,
    float* __restrict__ out) {
  __shared__ __align__(16) bf16_t AS[128 * 32];
  __shared__ __align__(16) bf16_t BS[128 * 32];
  const unsigned wg = (blockIdx.x & 7) * (gridDim.x >> 3) + (blockIdx.x >> 3);
  const int bn = wg % 5, bm = wg / 5;
  const int t = threadIdx.x, lane = t & 63, wid = t >> 6;
  const int wr = wid >> 1, wc = wid & 1;
  const int lm = lane & 15, quad = lane >> 4;
  const size_t brow0 = (size_t)bn * 128;
  const int cb = wid * 2;
  const int sx = (lm >> 1) & 3;

  // A chunk geometry: thread owns chunks 2t, 2t+1 (same row r0 = t>>1)
  const int r0    = t >> 1;
  const int row_g = bm * 128 + r0;
  const int qi    = (unsigned)row_g / NW;
  const float* fvrow = Fkv + (size_t)(QN + qi) * INNER;
  const float* dvrow = Dv + (size_t)row_g * 8;
  const int aslot[2] = { ((t * 2) & 3) ^ ((r0 >> 1) & 3),
                         ((t * 2 + 1) & 3) ^ ((r0 >> 1) & 3) };
  const int acol[2]  = { ((t * 2) & 3) * 8, ((t * 2 + 1) & 3) * 8 };

  auto STAGE_B = [&](int k0) {
#pragma unroll
    for (int tt = 0; tt < 2; ++tt) {
      int chunk = (cb + tt) * 64 + lane;
      int r = chunk >> 2;
      int c8 = (((chunk & 3) ^ ((r >> 1) & 3)) * 8);
      gl_lds16(Bh + (brow0 + r) * INNER + k0 + c8, &BS[(cb + tt) * 512]);
    }
  };

  f32x4 av[2][2];
  float dvv[2];
  auto LOAD_A = [&](int k0) {
#pragma unroll
    for (int u = 0; u < 2; ++u) {
      int col = k0 + acol[u];
      av[u][0] = *(const f32x4*)&fvrow[col];
      av[u][1] = *(const f32x4*)&fvrow[col + 4];
      dvv[u]   = dvrow[col >> 6];
    }
  };
  auto WRITE_A = [&]() {
#pragma unroll
    for (int u = 0; u < 2; ++u) {
      bf16x8 pk;
#pragma unroll
      for (int e = 0; e < 4; ++e) {
        pk[e]     = (bf16_t)(dvv[u] * av[u][0][e]);
        pk[e + 4] = (bf16_t)(dvv[u] * av[u][1][e]);
      }
      *(bf16x8*)&AS[r0 * 32 + aslot[u] * 8] = pk;
    }
  };

  f32x4 acc[4][4] = {};
  STAGE_B(0);
  LOAD_A(0);
  WRITE_A();
  __syncthreads();  // B landed (vmcnt0) + A ds_writes visible

  for (int k0 = 0; k0 < INNER; k0 += 32) {
    bf16x8 a[4], b[4];
#pragma unroll
    for (int i = 0; i < 4; ++i) {
      a[i] = *(const bf16x8*)&AS[(wr * 64 + i * 16 + lm) * 32 + (quad ^ sx) * 8];
      b[i] = *(const bf16x8*)&BS[(wc * 64 + i * 16 + lm) * 32 + (quad ^ sx) * 8];
    }
    __syncthreads();  // all reads done -> safe to overwrite both tiles
    const bool more = (k0 + 32 < INNER);
    if (more) { STAGE_B(k0 + 32); LOAD_A(k0 + 32); }  // latency hides under MFMA
#pragma unroll
    for (int mi = 0; mi < 4; ++mi)
#pragma unroll
      for (int nj = 0; nj < 4; ++nj)
        acc[mi][nj] =
            __builtin_amdgcn_mfma_f32_16x16x32_bf16(a[mi], b[nj], acc[mi][nj], 0, 0, 0);
    if (more) WRITE_A();  // compiler inserts vmcnt wait for av
    __syncthreads();      // next tile ready (B vmcnt drained, A writes visible)
  }
#pragma unroll
  for (int mi = 0; mi < 4; ++mi)
#pragma unroll
    for (int nj = 0; nj < 4; ++nj) {
      float bia = bias[bn * 128 + wc * 64 + nj * 16 + lm];
#pragma unroll
      for (int r = 0; r < 4; ++r) {
        int row = bm * 128 + wr * 64 + mi * 16 + quad * 4 + r;
        int col = bn * 128 + wc * 64 + nj * 16 + lm;
        out[(size_t)row * D + col] = acc[mi][nj][r] + bia;
      }
    }
}

extern "C" void kernel_launch(void* const* d_in, const int* in_sizes, int n_in,
                              void* d_out, int out_size, void* d_ws,
                              size_t ws_size, hipStream_t stream) {
  const float* q    = (const float*)d_in[0];
  const float* k    = (const float*)d_in[1];
  const float* v    = (const float*)d_in[2];
  const float* g    = (const float*)d_in[3];
  const float* b    = (const float*)d_in[4];
  const float* Win  = (const float*)d_in[5];
  const float* Wout = (const float*)d_in[6];
  const float* bout = (const float*)d_in[7];
  const float* vsp  = (const float*)d_in[8];
  const float* csp  = (const float*)d_in[9];
  float* out = (float*)d_out;

  char* w = (char*)d_ws;
  float* Fkv     = (float*)w;  w += (size_t)(2 * QN) * INNER * 4;   // 33.55 MB
  float* Sq      = (float*)w;  w += (size_t)MQ * 8 * 4;             // 1.31 MB
  float* Sqq     = (float*)w;  w += (size_t)MQ * 8 * 4;
  float* Sqk     = (float*)w;  w += (size_t)MQ * 8 * 4;
  float* Dv      = (float*)w;  w += (size_t)MQ * 8 * 4;             // 1.31 MB
  bf16_t* Ah     = (bf16_t*)w; w += (size_t)MQ * D * 2;             // 52.4 MB
  bf16_t* Al     = (bf16_t*)w; w += (size_t)MQ * D * 2;             // 52.4 MB
  bf16_t* WinTh  = (bf16_t*)w; w += (size_t)INNER * D * 2;
  bf16_t* WinTl  = (bf16_t*)w; w += (size_t)INNER * D * 2;
  bf16_t* WoutTh = (bf16_t*)w; w += (size_t)D * INNER * 2;
  bf16_t* WoutTl = (bf16_t*)w; w += (size_t)D * INNER * 2;

  transpose_split_kernel<<<dim3((D / 64) * (INNER / 64)), dim3(256), 0, stream>>>(
      Win, WinTh, WinTl, D, INNER);
  transpose_split_kernel<<<dim3((INNER / 64) * (D / 64)), dim3(256), 0, stream>>>(
      Wout, WoutTh, WoutTl, INNER, D);

  // --- k/v rows: LN-split then project -> Fkv (k 3-term, v 1-term) ---
  ln_split_kernel<<<dim3(2 * QN / 4), dim3(256), 0, stream>>>(
      q, k, v, g, b, Ah, Al, MQ);
  gemm1_kernel<0><<<dim3((2 * QN / 128) * 4), dim3(256), 0, stream>>>(
      Ah, Al, WinTh, WinTl, Fkv, nullptr, nullptr, nullptr, nullptr, 0);

  // --- all q rows in ONE launch (1280 blocks): fused stats ---
  ln_split_kernel<<<dim3(MQ / 4), dim3(256), 0, stream>>>(
      q, k, v, g, b, Ah, Al, 0);
  gemm1_kernel<1><<<dim3((MQ / 128) * 4), dim3(256), 0, stream>>>(
      Ah, Al, WinTh, WinTl, nullptr, Fkv, Sq, Sqq, Sqk, 0);

  // --- dots (Dv only), then output GEMM with on-the-fly A ---
  dots_kernel<<<dim3(QN * 8 / 4), dim3(256), 0, stream>>>(
      Fkv, Sq, Sqq, Sqk, vsp, csp, Dv);
  gemm2_kernel<<<dim3((MQ / 128) * 5), dim3(256), 0, stream>>>(
      Fkv, Dv, WoutTh, bout, out);
}